// Round 1
// baseline (183.106 us; speedup 1.0000x reference)
//
#include <hip/hip_runtime.h>
#include <cstddef>
#include <cstdint>

#define D_MODEL 512
#define DK 64
#define LQ 1024
#define LK 1024
#define NB 2
#define LN_EPS 1e-6f

// tanh(x) = 1 - 2/(exp(2x)+1); exp via hardware v_exp_f32, rcp via v_rcp_f32.
// abs error ~1e-6 -- far below the 0.1 harness threshold.
__device__ __forceinline__ float fast_tanh(float x) {
  float e = __builtin_amdgcn_exp2f(x * 2.8853900817779268f);  // exp(2x)
  return 1.0f - 2.0f * __builtin_amdgcn_rcpf(e + 1.0f);
}

// ---------------- projections: qp = q@Wq, kp = k@Wk, vp = v@Wv ----------------
// grid = B*LQ/4 blocks, 192 threads (3 waves: one per projection).
// Input rows staged in LDS (broadcast reads); W column reads are coalesced
// (lane d reads W[e*64+d], 256B/wave) and L2-resident.
#define ROWS_P 4
__global__ __launch_bounds__(192) void proj_kernel(
    const float* __restrict__ q, const float* __restrict__ k,
    const float* __restrict__ v, const float* __restrict__ Wq,
    const float* __restrict__ Wk, const float* __restrict__ Wv,
    float* __restrict__ qp, float* __restrict__ kp, float* __restrict__ vp) {
  __shared__ float rows[ROWS_P][3][D_MODEL];
  const int row0 = blockIdx.x * ROWS_P;
  const int tid = threadIdx.x;
  for (int i = tid; i < ROWS_P * D_MODEL; i += 192) {
    int r = i >> 9, e = i & (D_MODEL - 1);
    size_t g = (size_t)(row0 + r) * D_MODEL + e;
    rows[r][0][e] = q[g];
    rows[r][1][e] = k[g];
    rows[r][2][e] = v[g];
  }
  __syncthreads();
  const int which = tid >> 6;  // 0=q,1=k,2=v
  const int d = tid & 63;
  const float* __restrict__ W = (which == 0) ? Wq : (which == 1) ? Wk : Wv;
  float acc[ROWS_P];
#pragma unroll
  for (int r = 0; r < ROWS_P; ++r) acc[r] = 0.f;
  for (int e = 0; e < D_MODEL; ++e) {
    float w = W[e * DK + d];
#pragma unroll
    for (int r = 0; r < ROWS_P; ++r) acc[r] += rows[r][which][e] * w;
  }
  float* __restrict__ outp = (which == 0) ? qp : (which == 1) ? kp : vp;
#pragma unroll
  for (int r = 0; r < ROWS_P; ++r)
    outp[(size_t)(row0 + r) * DK + d] = acc[r];
}

// ---------------- scores + softmax + attn@vp ----------------
// grid = B*LQ/4, 256 threads. Thread owns j = tid&127 for 2 rows (sub = tid>>7).
// kp tile staged into LDS with rotate-by-j swizzle: coalesced global loads,
// conflict-free (2-way) LDS reads. q-rows + v_param packed as one float4
// broadcast per d.
#define RB 4
#define TJ 128
__global__ __launch_bounds__(256) void attn_kernel(
    const float* __restrict__ qp, const float* __restrict__ kp,
    const float* __restrict__ vp, const float* __restrict__ v_param,
    float* __restrict__ attn_out,   // [B, LQ, LK]
    float* __restrict__ ov_out) {   // [B*LQ, 64]
  __shared__ float kt[TJ][64];      // swizzled kp tile
  __shared__ float sc[RB][LK];      // scores -> probabilities
  __shared__ float4 qv[2][64];      // {q[r0][d], q[r0+1][d], v_param[d], 0}
  const int tid = threadIdx.x;
  const int row0 = blockIdx.x * RB;      // RB divides LQ -> single batch/block
  const int batch = row0 / LQ;
  const float* __restrict__ kp_b = kp + (size_t)batch * LK * DK;
  const float* __restrict__ vp_b = vp + (size_t)batch * LK * DK;

  if (tid < 2 * 64) {
    int s = tid >> 6, d = tid & 63;
    int r0 = s * 2;
    qv[s][d] = make_float4(qp[(size_t)(row0 + r0) * DK + d],
                           qp[(size_t)(row0 + r0 + 1) * DK + d],
                           v_param[d], 0.f);
  }

  const int jl = tid & (TJ - 1);
  const int sub = tid >> 7;

  for (int jt = 0; jt < LK / TJ; ++jt) {
    __syncthreads();  // previous tile consumed (also covers qv staging)
    const float* __restrict__ src = kp_b + (size_t)jt * TJ * DK;
    for (int i = tid; i < TJ * DK; i += 256) {
      int j = i >> 6, d = i & 63;
      kt[j][(d + j) & 63] = src[i];
    }
    __syncthreads();
    float s0 = 0.f, s1 = 0.f;
#pragma unroll 16
    for (int d = 0; d < 64; ++d) {
      float kv = kt[jl][(d + jl) & 63];
      float4 qq = qv[sub][d];
      s0 += fast_tanh(qq.x + kv) * qq.z;
      s1 += fast_tanh(qq.y + kv) * qq.z;
    }
    sc[sub * 2 + 0][jt * TJ + jl] = s0;
    sc[sub * 2 + 1][jt * TJ + jl] = s1;
  }
  __syncthreads();

  // softmax: wave w handles row w; 16 j per lane kept in registers
  {
    const int wv = tid >> 6, lane = tid & 63;
    float m = -1e30f;
#pragma unroll
    for (int i = 0; i < LK / 64; ++i) m = fmaxf(m, sc[wv][i * 64 + lane]);
#pragma unroll
    for (int off = 32; off > 0; off >>= 1) m = fmaxf(m, __shfl_xor(m, off));
    float p[LK / 64];
    float ssum = 0.f;
#pragma unroll
    for (int i = 0; i < LK / 64; ++i) {
      float e = __builtin_amdgcn_exp2f((sc[wv][i * 64 + lane] - m) *
                                       1.4426950408889634f);
      p[i] = e;
      ssum += e;
    }
#pragma unroll
    for (int off = 32; off > 0; off >>= 1) ssum += __shfl_xor(ssum, off);
    float inv = __builtin_amdgcn_rcpf(ssum);
    float* __restrict__ arow = attn_out + (size_t)(row0 + wv) * LK;
#pragma unroll
    for (int i = 0; i < LK / 64; ++i) {
      float pn = p[i] * inv;
      sc[wv][i * 64 + lane] = pn;   // keep for PV pass
      arow[i * 64 + lane] = pn;     // coalesced output
    }
  }
  __syncthreads();

  // PV: wave = row; lanes (jj,l16) cover 4 j in flight x 16 float4 columns
  {
    const int r = tid >> 6, lane = tid & 63;
    const int jj = lane >> 4, l16 = lane & 15;
    const float4* __restrict__ vp4 = (const float4*)vp_b;
    float ax = 0.f, ay = 0.f, az = 0.f, aw = 0.f;
    for (int j = jj; j < LK; j += 4) {
      float pw = sc[r][j];
      float4 vv = vp4[(size_t)j * (DK / 4) + l16];
      ax += pw * vv.x; ay += pw * vv.y; az += pw * vv.z; aw += pw * vv.w;
    }
    ax += __shfl_xor(ax, 16); ay += __shfl_xor(ay, 16);
    az += __shfl_xor(az, 16); aw += __shfl_xor(aw, 16);
    ax += __shfl_xor(ax, 32); ay += __shfl_xor(ay, 32);
    az += __shfl_xor(az, 32); aw += __shfl_xor(aw, 32);
    if (jj == 0) {
      float4* o4 = (float4*)(ov_out + (size_t)(row0 + r) * DK);
      o4[l16] = make_float4(ax, ay, az, aw);
    }
  }
}

// ---------------- out = LN(ov@Wfc + residual) ----------------
// grid = B*LQ/4, 256 threads; thread owns columns c and c+256 of 4 rows.
#define ROWS_C 4
__global__ __launch_bounds__(256) void fc_ln_kernel(
    const float* __restrict__ ov, const float* __restrict__ Wfc,
    const float* __restrict__ resid, const float* __restrict__ gamma,
    const float* __restrict__ beta, float* __restrict__ out) {
  __shared__ float o_lds[ROWS_C][DK];
  __shared__ float red[2][ROWS_C][4];
  const int row0 = blockIdx.x * ROWS_C;
  const int tid = threadIdx.x;
  if (tid < ROWS_C * DK) {
    int r = tid >> 6, d = tid & 63;
    o_lds[r][d] = ov[(size_t)(row0 + r) * DK + d];
  }
  __syncthreads();
  const int c0 = tid, c1 = tid + 256;
  float y[ROWS_C][2];
#pragma unroll
  for (int r = 0; r < ROWS_C; ++r) {
    y[r][0] = resid[(size_t)(row0 + r) * D_MODEL + c0];
    y[r][1] = resid[(size_t)(row0 + r) * D_MODEL + c1];
  }
  for (int e = 0; e < DK; ++e) {
    float w0 = Wfc[e * D_MODEL + c0];
    float w1 = Wfc[e * D_MODEL + c1];
#pragma unroll
    for (int r = 0; r < ROWS_C; ++r) {
      float o = o_lds[r][e];
      y[r][0] += o * w0;
      y[r][1] += o * w1;
    }
  }
  const int wv = tid >> 6, lane = tid & 63;
#pragma unroll
  for (int r = 0; r < ROWS_C; ++r) {
    float s = y[r][0] + y[r][1];
#pragma unroll
    for (int off = 32; off > 0; off >>= 1) s += __shfl_xor(s, off);
    if (lane == 0) red[0][r][wv] = s;
  }
  __syncthreads();
  float mu[ROWS_C];
#pragma unroll
  for (int r = 0; r < ROWS_C; ++r)
    mu[r] = (red[0][r][0] + red[0][r][1] + red[0][r][2] + red[0][r][3]) *
            (1.0f / D_MODEL);
#pragma unroll
  for (int r = 0; r < ROWS_C; ++r) {
    float d0 = y[r][0] - mu[r], d1 = y[r][1] - mu[r];
    float s = d0 * d0 + d1 * d1;
#pragma unroll
    for (int off = 32; off > 0; off >>= 1) s += __shfl_xor(s, off);
    if (lane == 0) red[1][r][wv] = s;
  }
  __syncthreads();
  float g0 = gamma[c0], g1 = gamma[c1], b0 = beta[c0], b1 = beta[c1];
#pragma unroll
  for (int r = 0; r < ROWS_C; ++r) {
    float var = (red[1][r][0] + red[1][r][1] + red[1][r][2] + red[1][r][3]) *
                (1.0f / D_MODEL);
    float rstd = rsqrtf(var + LN_EPS);
    out[(size_t)(row0 + r) * D_MODEL + c0] = (y[r][0] - mu[r]) * rstd * g0 + b0;
    out[(size_t)(row0 + r) * D_MODEL + c1] = (y[r][1] - mu[r]) * rstd * g1 + b1;
  }
}

extern "C" void kernel_launch(void* const* d_in, const int* in_sizes, int n_in,
                              void* d_out, int out_size, void* d_ws,
                              size_t ws_size, hipStream_t stream) {
  const float* q = (const float*)d_in[0];
  const float* k = (const float*)d_in[1];
  const float* v = (const float*)d_in[2];
  const float* Wq = (const float*)d_in[3];
  const float* Wk = (const float*)d_in[4];
  const float* Wv = (const float*)d_in[5];
  const float* v_param = (const float*)d_in[6];
  const float* Wfc = (const float*)d_in[7];
  const float* gamma = (const float*)d_in[8];
  const float* beta = (const float*)d_in[9];

  float* out = (float*)d_out;                          // [B*LQ*D_MODEL]
  float* attn = out + (size_t)NB * LQ * D_MODEL;       // [B*LQ*LK]

  float* qp = (float*)d_ws;                            // [B*LQ*DK]
  float* kp = qp + (size_t)NB * LQ * DK;
  float* vp = kp + (size_t)NB * LK * DK;
  float* ov = vp + (size_t)NB * LK * DK;               // [B*LQ*DK]

  hipLaunchKernelGGL(proj_kernel, dim3(NB * LQ / ROWS_P), dim3(192), 0, stream,
                     q, k, v, Wq, Wk, Wv, qp, kp, vp);
  hipLaunchKernelGGL(attn_kernel, dim3(NB * LQ / RB), dim3(256), 0, stream,
                     qp, kp, vp, v_param, attn, ov);
  hipLaunchKernelGGL(fc_ln_kernel, dim3(NB * LQ / ROWS_C), dim3(256), 0, stream,
                     ov, Wfc, q, gamma, beta, out);
}

// Round 2
// 69.128 us; speedup vs baseline: 2.6488x; 2.6488x over previous
//
#include <hip/hip_runtime.h>
#include <cstddef>
#include <cstdint>

#define D_MODEL 512
#define DK 64
#define LQ 1024
#define LK 1024
#define NB 2
#define LN_EPS 1e-6f
#define L2E2 2.8853900817779268f  // 2*log2(e)

// ---------------- projections ----------------
// eq = exp(2*(q@Wq)), ek = exp(2*(k@Wk)), vp = v@Wv
// tanh(a+b) = 1 - 2/(e^{2a} e^{2b} + 1) -> scores via 1 rcp per element later.
#define ROWS_P 4
__global__ __launch_bounds__(192) void proj_kernel(
    const float* __restrict__ q, const float* __restrict__ k,
    const float* __restrict__ v, const float* __restrict__ Wq,
    const float* __restrict__ Wk, const float* __restrict__ Wv,
    float* __restrict__ eq, float* __restrict__ ek, float* __restrict__ vp) {
  __shared__ float rows[ROWS_P][3][D_MODEL];
  const int row0 = blockIdx.x * ROWS_P;
  const int tid = threadIdx.x;
  for (int i = tid; i < ROWS_P * D_MODEL; i += 192) {
    int r = i >> 9, e = i & (D_MODEL - 1);
    size_t g = (size_t)(row0 + r) * D_MODEL + e;
    rows[r][0][e] = q[g];
    rows[r][1][e] = k[g];
    rows[r][2][e] = v[g];
  }
  __syncthreads();
  const int which = tid >> 6;  // 0=q,1=k,2=v
  const int d = tid & 63;
  const float* __restrict__ W = (which == 0) ? Wq : (which == 1) ? Wk : Wv;
  float acc[ROWS_P];
#pragma unroll
  for (int r = 0; r < ROWS_P; ++r) acc[r] = 0.f;
  for (int e = 0; e < D_MODEL; ++e) {
    float w = W[e * DK + d];
#pragma unroll
    for (int r = 0; r < ROWS_P; ++r) acc[r] += rows[r][which][e] * w;
  }
  float* __restrict__ outp = (which == 0) ? eq : (which == 1) ? ek : vp;
#pragma unroll
  for (int r = 0; r < ROWS_P; ++r) {
    float val = acc[r];
    if (which < 2) val = __builtin_amdgcn_exp2f(val * L2E2);  // e^{2x}
    outp[(size_t)(row0 + r) * DK + d] = val;
  }
}

// ---------------- scores + softmax + attn@vp ----------------
// 512 threads (8 waves), RB=4 rows/block, grid 512 (2 blocks/CU, 16 waves/CU).
// Thread owns (row sub = tid>>7, j = tid&127). Ek tile in LDS (rotate swizzle,
// conflict-free); Eq row + v_param via wave-uniform scalar loads. Register
// prefetch of tile t+1 overlaps global latency with tile-t compute.
#define RB 4
#define TJ 128
#define NT (LK / TJ)
__global__ __launch_bounds__(512, 4) void attn_kernel(
    const float* __restrict__ eq, const float* __restrict__ ek,
    const float* __restrict__ vp, const float* __restrict__ v_param,
    float* __restrict__ attn_out,  // [B, LQ, LK]
    float* __restrict__ ov_out) {  // [B*LQ, 64]
  __shared__ __align__(16) float kt[TJ][64];  // 32 KiB, rotate-by-j swizzle
  __shared__ float sc[RB][LK];                // 16 KiB: scores -> probs
  const int tid = threadIdx.x;
  const int row0 = blockIdx.x * RB;  // RB | LQ -> single batch per block
  const int batch = row0 >> 10;
  const float* __restrict__ ek_b = ek + (size_t)batch * LK * DK;
  const float* __restrict__ vp_b = vp + (size_t)batch * LK * DK;
  const int jl = tid & (TJ - 1);
  const int sub = __builtin_amdgcn_readfirstlane(tid >> 7);  // wave-uniform row
  const float* __restrict__ eqrow = eq + (size_t)(row0 + sub) * DK;

  float4 vreg[4];
  {
    const float4* __restrict__ s4 = (const float4*)ek_b;
#pragma unroll
    for (int t = 0; t < 4; ++t) vreg[t] = s4[tid + 512 * t];
  }
  // stage tile 0
#pragma unroll
  for (int t = 0; t < 4; ++t) {
    int i = tid + 512 * t;
    int j = i >> 4, d0 = (i & 15) * 4;
    kt[j][(d0 + 0 + j) & 63] = vreg[t].x;
    kt[j][(d0 + 1 + j) & 63] = vreg[t].y;
    kt[j][(d0 + 2 + j) & 63] = vreg[t].z;
    kt[j][(d0 + 3 + j) & 63] = vreg[t].w;
  }
  __syncthreads();

  for (int jt = 0; jt < NT; ++jt) {
    if (jt + 1 < NT) {  // issue next-tile loads; latency hides under compute
      const float4* __restrict__ s4 =
          (const float4*)(ek_b + (size_t)(jt + 1) * TJ * DK);
#pragma unroll
      for (int t = 0; t < 4; ++t) vreg[t] = s4[tid + 512 * t];
    }
    float acc = 0.f;
#pragma unroll
    for (int d = 0; d < 64; ++d) {
      float kv = kt[jl][(d + jl) & 63];
      float t1 = fmaf(eqrow[d], kv, 1.0f);
      acc = fmaf(v_param[d], __builtin_amdgcn_rcpf(t1), acc);
    }
    sc[sub][jt * TJ + jl] = acc;  // score_j = const - 2*acc; const drops in softmax
    __syncthreads();
    if (jt + 1 < NT) {
#pragma unroll
      for (int t = 0; t < 4; ++t) {
        int i = tid + 512 * t;
        int j = i >> 4, d0 = (i & 15) * 4;
        kt[j][(d0 + 0 + j) & 63] = vreg[t].x;
        kt[j][(d0 + 1 + j) & 63] = vreg[t].y;
        kt[j][(d0 + 2 + j) & 63] = vreg[t].z;
        kt[j][(d0 + 3 + j) & 63] = vreg[t].w;
      }
      __syncthreads();
    }
  }

  const int wave = __builtin_amdgcn_readfirstlane(tid >> 6);
  const int lane = tid & 63;

  // softmax over a_j = -2*s_j  ->  shift by min(s); waves 0..3 = rows 0..3
  if (wave < RB) {
    const int r = wave;
    float m = 1e30f;
#pragma unroll
    for (int i = 0; i < LK / 64; ++i) m = fminf(m, sc[r][i * 64 + lane]);
#pragma unroll
    for (int off = 32; off > 0; off >>= 1) m = fminf(m, __shfl_xor(m, off));
    float p[LK / 64];
    float ssum = 0.f;
#pragma unroll
    for (int i = 0; i < LK / 64; ++i) {
      float e = __builtin_amdgcn_exp2f((m - sc[r][i * 64 + lane]) * L2E2);
      p[i] = e;
      ssum += e;
    }
#pragma unroll
    for (int off = 32; off > 0; off >>= 1) ssum += __shfl_xor(ssum, off);
    float inv = __builtin_amdgcn_rcpf(ssum);
    float* __restrict__ arow = attn_out + (size_t)(row0 + r) * LK;
#pragma unroll
    for (int i = 0; i < LK / 64; ++i) {
      float pn = p[i] * inv;
      sc[r][i * 64 + lane] = pn;  // keep for PV
      arow[i * 64 + lane] = pn;   // coalesced output
    }
  }
  __syncthreads();

  // PV: wave owns a 128-j slice; vp read ONCE per block per j (serves 4 rows).
  float4* red4 = (float4*)&kt[0][0];  // overlay: kt is dead now (8 KiB used)
  {
    const int jj = lane >> 4, l16 = lane & 15;
    const float4* __restrict__ vp4 = (const float4*)vp_b;
    float4 a[RB];
#pragma unroll
    for (int r = 0; r < RB; ++r) a[r] = make_float4(0.f, 0.f, 0.f, 0.f);
#pragma unroll 4
    for (int it = 0; it < TJ / 4; ++it) {
      int j = wave * TJ + it * 4 + jj;
      float4 vv = vp4[(size_t)j * (DK / 4) + l16];
#pragma unroll
      for (int r = 0; r < RB; ++r) {
        float pw = sc[r][j];
        a[r].x += pw * vv.x; a[r].y += pw * vv.y;
        a[r].z += pw * vv.z; a[r].w += pw * vv.w;
      }
    }
#pragma unroll
    for (int r = 0; r < RB; ++r) {
      a[r].x += __shfl_xor(a[r].x, 16); a[r].y += __shfl_xor(a[r].y, 16);
      a[r].z += __shfl_xor(a[r].z, 16); a[r].w += __shfl_xor(a[r].w, 16);
      a[r].x += __shfl_xor(a[r].x, 32); a[r].y += __shfl_xor(a[r].y, 32);
      a[r].z += __shfl_xor(a[r].z, 32); a[r].w += __shfl_xor(a[r].w, 32);
    }
    if (jj == 0) {
#pragma unroll
      for (int r = 0; r < RB; ++r) red4[(wave * RB + r) * 16 + l16] = a[r];
    }
  }
  __syncthreads();
  if (tid < 64) {
    int r = tid >> 4, l16 = tid & 15;
    float4 s = make_float4(0.f, 0.f, 0.f, 0.f);
#pragma unroll
    for (int w = 0; w < 8; ++w) {
      float4 t = red4[(w * RB + r) * 16 + l16];
      s.x += t.x; s.y += t.y; s.z += t.z; s.w += t.w;
    }
    ((float4*)(ov_out + (size_t)(row0 + r) * DK))[l16] = s;
  }
}

// ---------------- out = LN(ov@Wfc + residual) ----------------
#define ROWS_C 4
__global__ __launch_bounds__(256) void fc_ln_kernel(
    const float* __restrict__ ov, const float* __restrict__ Wfc,
    const float* __restrict__ resid, const float* __restrict__ gamma,
    const float* __restrict__ beta, float* __restrict__ out) {
  __shared__ float o_lds[ROWS_C][DK];
  __shared__ float red[2][ROWS_C][4];
  const int row0 = blockIdx.x * ROWS_C;
  const int tid = threadIdx.x;
  if (tid < ROWS_C * DK) {
    int r = tid >> 6, d = tid & 63;
    o_lds[r][d] = ov[(size_t)(row0 + r) * DK + d];
  }
  __syncthreads();
  const int c0 = tid, c1 = tid + 256;
  float y[ROWS_C][2];
#pragma unroll
  for (int r = 0; r < ROWS_C; ++r) {
    y[r][0] = resid[(size_t)(row0 + r) * D_MODEL + c0];
    y[r][1] = resid[(size_t)(row0 + r) * D_MODEL + c1];
  }
  for (int e = 0; e < DK; ++e) {
    float w0 = Wfc[e * D_MODEL + c0];
    float w1 = Wfc[e * D_MODEL + c1];
#pragma unroll
    for (int r = 0; r < ROWS_C; ++r) {
      float o = o_lds[r][e];
      y[r][0] += o * w0;
      y[r][1] += o * w1;
    }
  }
  const int wv = tid >> 6, lane = tid & 63;
#pragma unroll
  for (int r = 0; r < ROWS_C; ++r) {
    float s = y[r][0] + y[r][1];
#pragma unroll
    for (int off = 32; off > 0; off >>= 1) s += __shfl_xor(s, off);
    if (lane == 0) red[0][r][wv] = s;
  }
  __syncthreads();
  float mu[ROWS_C];
#pragma unroll
  for (int r = 0; r < ROWS_C; ++r)
    mu[r] = (red[0][r][0] + red[0][r][1] + red[0][r][2] + red[0][r][3]) *
            (1.0f / D_MODEL);
#pragma unroll
  for (int r = 0; r < ROWS_C; ++r) {
    float d0 = y[r][0] - mu[r], d1 = y[r][1] - mu[r];
    float s = d0 * d0 + d1 * d1;
#pragma unroll
    for (int off = 32; off > 0; off >>= 1) s += __shfl_xor(s, off);
    if (lane == 0) red[1][r][wv] = s;
  }
  __syncthreads();
  float g0 = gamma[c0], g1 = gamma[c1], b0 = beta[c0], b1 = beta[c1];
#pragma unroll
  for (int r = 0; r < ROWS_C; ++r) {
    float var = (red[1][r][0] + red[1][r][1] + red[1][r][2] + red[1][r][3]) *
                (1.0f / D_MODEL);
    float rstd = rsqrtf(var + LN_EPS);
    out[(size_t)(row0 + r) * D_MODEL + c0] = (y[r][0] - mu[r]) * rstd * g0 + b0;
    out[(size_t)(row0 + r) * D_MODEL + c1] = (y[r][1] - mu[r]) * rstd * g1 + b1;
  }
}

extern "C" void kernel_launch(void* const* d_in, const int* in_sizes, int n_in,
                              void* d_out, int out_size, void* d_ws,
                              size_t ws_size, hipStream_t stream) {
  const float* q = (const float*)d_in[0];
  const float* k = (const float*)d_in[1];
  const float* v = (const float*)d_in[2];
  const float* Wq = (const float*)d_in[3];
  const float* Wk = (const float*)d_in[4];
  const float* Wv = (const float*)d_in[5];
  const float* v_param = (const float*)d_in[6];
  const float* Wfc = (const float*)d_in[7];
  const float* gamma = (const float*)d_in[8];
  const float* beta = (const float*)d_in[9];

  float* out = (float*)d_out;                     // [B*LQ*D_MODEL]
  float* attn = out + (size_t)NB * LQ * D_MODEL;  // [B*LQ*LK]

  float* eq = (float*)d_ws;  // exp(2*qp)  [B*LQ*DK]
  float* ek = eq + (size_t)NB * LQ * DK;
  float* vp = ek + (size_t)NB * LK * DK;
  float* ov = vp + (size_t)NB * LK * DK;

  hipLaunchKernelGGL(proj_kernel, dim3(NB * LQ / ROWS_P), dim3(192), 0, stream,
                     q, k, v, Wq, Wk, Wv, eq, ek, vp);
  hipLaunchKernelGGL(attn_kernel, dim3(NB * LQ / RB), dim3(512), 0, stream,
                     eq, ek, vp, v_param, attn, ov);
  hipLaunchKernelGGL(fc_ln_kernel, dim3(NB * LQ / ROWS_C), dim3(256), 0, stream,
                     ov, Wfc, q, gamma, beta, out);
}